// Round 7
// baseline (3448.912 us; speedup 1.0000x reference)
//
#include <hip/hip_runtime.h>
#include <stdint.h>

// Bidirectional GRU, 6 layers, H=256, S=512, B=10, fp32 in/out, bf16 MFMA.
// 7 live scans + 42 helper WGs (6/stream), gates via global_load_lds (SC1).
// THIS ROUND — attack producer rate + slow-path re-serialization:
//   r6 (dma slack 1.0->1.9) = null => consumer VMEM latency not binding.
//   New theory: helpers (3/stream, T_h ~ 10us: h-load RTT + 32KB sc1 publish
//   + in-loop vm0) cap slot rate at T_h/3 ~ 3.3us = measured step; and when
//   helpers are just-in-time the LDS tag mirror is always stale => slow path
//   => r6's "slow -> wait_vm0" re-serializes a full drain EVERY step.
//   1) 6 helpers/stream (grid 49): slot interval halves. Flow-control at
//      t+=6 audited: writer needs cparr >= t-24; prior-generation DMA
//      drained by F(t-33) => 8-step margin.
//   2) slow no longer forces wait_vm0 at F: the slow poll already drains
//      all VMEM inside the poll loop, so the steady counted waits are
//      over-satisfied (<=6 in flight vs keep 8/6/4) => provably safe.
// Scan otherwise byte-identical to round 6 (3371us verified).

typedef short short8 __attribute__((ext_vector_type(8)));
typedef float floatx4 __attribute__((ext_vector_type(4)));
typedef unsigned long long u64;
typedef unsigned int u32;
typedef unsigned short u16;

#define SEQ 512

// ws: gring 7*32 slots x 32KB (rz bf16 [512][16] + nx f32 [256][16]) = 7.34MB
//     hh   scans 0..4 [t:512][b:16][ch:128] bf16 = 10.5MB
//     tags u32: gtag[7][32] @0 ; htag[5][512] @256 ; cparr[7] @2816
#define GSLOT_U64 4096
#define GRING_U64 (7 * 32 * GSLOT_U64)
#define HH_U16 (5 * 512 * 2048)
#define TAGS_OFF_B ((size_t)GRING_U64 * 8 + (size_t)HH_U16 * 2)

__device__ __forceinline__ u16 f2bf(float f){ union{float f;u32 i;}v; v.f=f; u32 u=v.i; u += 0x7fffu + ((u>>16)&1u); return (u16)(u>>16); }
__device__ __forceinline__ float bf2f(u16 h){ union{u32 i;float f;}v; v.i=((u32)h)<<16; return v.f; }
__device__ __forceinline__ short8 ld8f(const float* p){
    float4 a=*(const float4*)p, b=*(const float4*)(p+4);
    short8 r; r[0]=(short)f2bf(a.x); r[1]=(short)f2bf(a.y); r[2]=(short)f2bf(a.z); r[3]=(short)f2bf(a.w);
    r[4]=(short)f2bf(b.x); r[5]=(short)f2bf(b.y); r[6]=(short)f2bf(b.z); r[7]=(short)f2bf(b.w); return r;
}
__device__ __forceinline__ short8 pk2(u64 a, u64 b){ union{u64 q[2]; short8 s;}v; v.q[0]=a; v.q[1]=b; return v.s; }
__device__ __forceinline__ u64 pack4bf(floatx4 a){
    return (u64)f2bf(a[0]) | ((u64)f2bf(a[1])<<16) | ((u64)f2bf(a[2])<<32) | ((u64)f2bf(a[3])<<48);
}
// fast reciprocal (v_rcp_f32, ~1 ulp; validated r5/r6: absmax unchanged)
__device__ __forceinline__ float rcp_(float x){ float r; asm("v_rcp_f32 %0, %1" : "=v"(r) : "v"(x)); return r; }
__device__ __forceinline__ float sigmoidf_(float x){ return rcp_(1.0f + __expf(-x)); }
__device__ __forceinline__ float tanhf_(float x){ return 1.0f - 2.0f*rcp_(__expf(2.0f*x) + 1.0f); }

#define ALD(p)    __hip_atomic_load((p), __ATOMIC_RELAXED, __HIP_MEMORY_SCOPE_AGENT)
#define AST(p,v)  __hip_atomic_store((p),(v),__ATOMIC_RELAXED,__HIP_MEMORY_SCOPE_AGENT)
__device__ __forceinline__ void wait_vm0(){ asm volatile("s_waitcnt vmcnt(0)" ::: "memory"); }
#define WVC(n) asm volatile("s_waitcnt vmcnt(" #n ")" ::: "memory")
__device__ __forceinline__ void lgkm_barrier(){ asm volatile("s_waitcnt lgkmcnt(0)\n\ts_barrier" ::: "memory"); }

// 16B device-scope (MALL-visible) store: sc1 cache policy at dwordx4 width.
__device__ __forceinline__ void st16_sc1(void* p, floatx4 v){
    asm volatile("global_store_dwordx4 %0, %1, off sc1" :: "v"(p), "v"(v) : "memory");
}

// global->LDS DMA, SC1 (device-scope, bypass per-XCD L2)
__device__ __forceinline__ void dma16(const void* g, void* l) {
    __builtin_amdgcn_global_load_lds(
        reinterpret_cast<const __attribute__((address_space(1))) unsigned int*>(
            (uintptr_t)g),
        reinterpret_cast<__attribute__((address_space(3))) unsigned int*>(
            (uintptr_t)l), 16, 0, 16);
}
__device__ __forceinline__ void dma4(const void* g, void* l) {
    __builtin_amdgcn_global_load_lds(
        reinterpret_cast<const __attribute__((address_space(1))) unsigned int*>(
            (uintptr_t)g),
        reinterpret_cast<__attribute__((address_space(3))) unsigned int*>(
            (uintptr_t)l), 4, 0, 16);
}

__global__ __launch_bounds__(512, 2)
void gru_pipeline(const float* __restrict__ x,
                  const float* __restrict__ wihl0,
                  const float* __restrict__ wihrest,
                  const float* __restrict__ whh,
                  float* __restrict__ out,
                  u64* __restrict__ gring,
                  u16* __restrict__ hhb,
                  u32* __restrict__ tags)
{
    __shared__ u64 smem_[14404];   // 115,232 B: gbuf 3x32768 + hbuf 16,896 + tagmir 16
    const int blk  = blockIdx.x;
    const int tid  = threadIdx.x;
    const int w    = tid >> 6;
    const int lane = tid & 63;
    const int n16  = lane & 15;
    const int quad = lane >> 4;
    u32* cparr = tags + 2816;

    if (blk < 7) {
        // ================= SCAN: one 512-thread WG per scan =================
        const int s = blk;
        const int wu = __builtin_amdgcn_readfirstlane(tid) >> 6;   // wave idx, SGPR
        const int layer = (s==6)?5:s, dir=(s==6)?1:0;
        const float* whhp = whh + ((size_t)(layer*2+dir))*768*256;

        // W_hh B-frags: wave owns units j in [32w,32w+32): tiles m=g*2+u
        short8 bh[6][8];
#pragma unroll
        for (int g=0; g<3; ++g)
#pragma unroll
        for (int u=0; u<2; ++u) {
            const int row = g*256 + 32*w + 16*u + n16;
#pragma unroll
            for (int q=0; q<8; ++q)
                bh[g*2+u][q] = ld8f(whhp + (size_t)row*256 + q*32 + quad*8);
        }

        char* gb   = (char*)smem_;                      // gate slots: [3][32768 B]
        u16*  hbuf = (u16*)(gb + 98304);                // [2][16][264] bf16
        u32*  tagmir = (u32*)((char*)smem_ + 115200);   // [4] gtag mirror ring
        for (int i=tid; i<8448; i+=512) hbuf[i] = 0;    // h(-1)=0 (both slots)

        u32* gtp = tags + s*32;
        u32* htp = tags + 256 + s*512;

        // prologue: stage gates(0), gates(1); mirror tags for slots 2,3
        {
            int gd=0;
            while (ALD(gtp + 0) != 1u){ if(++gd>3000000) break; __builtin_amdgcn_s_sleep(2); }
            const char* sg = (const char*)(gring + (size_t)(s*32)*GSLOT_U64);
#pragma unroll
            for (int r=0; r<4; ++r) dma16(sg + (r*512+tid)*16, gb + (r*512+tid)*16);
            gd=0;
            while (ALD(gtp + 1) != 2u){ if(++gd>3000000) break; __builtin_amdgcn_s_sleep(2); }
            sg = (const char*)(gring + (size_t)(s*32 + 1)*GSLOT_U64);
#pragma unroll
            for (int r=0; r<4; ++r) dma16(sg + (r*512+tid)*16, gb + 32768 + (r*512+tid)*16);
            if (tid==0) { dma4(gtp + 2, tagmir + 2); dma4(gtp + 3, tagmir + 3); }
            wait_vm0(); lgkm_barrier();
        }

        for (int t=0; t<SEQ; ++t) {
            const u16* hbP = hbuf + (t&1)*4224;
            // A (post-barrier): tags, mirror check, tagdma(t+4), dma(t+2).
            // Slot (t+2)%3's previous readers = D/E(t-1), barrier-separated.
            // htag(t-4): hstore(t-4)@B(t-3) provably drained by F(t-1).
            if (wu == 0) {
                if ((t&3)==0) AST(cparr + s, (u32)(t+1));
                if (s<=4 && t>=4) AST(htp + (t-4), (u32)(t-3));
            }
            if (t+2 < SEQ) {
                if (tagmir[(t+2)&3] != (u32)(t+3)) {
                    // slow path: global poll. The branch-consumed load drains
                    // all VMEM each poll iter => afterwards in-flight = only
                    // ops issued below => steady counted waits at F remain
                    // safe (over-satisfied). No forced vm0 at F anymore.
                    int gd=0;
                    while (ALD(gtp + ((t+2)&31)) != (u32)(t+3)){ if(++gd>3000000) break; __builtin_amdgcn_s_sleep(1); }
                }
                if (wu==0 && lane==0 && t+4 < SEQ)
                    dma4(gtp + ((t+4)&31), tagmir + ((t+4)&3));
                const char* sg = (const char*)(gring + (size_t)(s*32 + ((t+2)&31))*GSLOT_U64);
                char* dg = gb + ((t+2)%3)*32768;
#pragma unroll
                for (int r=0; r<4; ++r) dma16(sg + (r*512+tid)*16, dg + (r*512+tid)*16);
            }

            // B: publish h(t-1) / out(t-1) from LDS slot t&1
            if (t >= 1) {
                if (s<=4) {
                    if (wu < 4) {       // tid<256: b = tid&15, 16B chunk k
                        const int b = tid & 15, k = (tid >> 4) & 15;
                        char* hq = (char*)(hhb + (size_t)s*1048576 + (size_t)(t-1)*2048);
                        st16_sc1(hq + b*256 + k*16, *(const floatx4*)(hbP + b*264 + 8*k));
                    }
                } else {
                    const int off = (s==6)?256:0;
                    {   // store 0: all 512 threads
                        const int b = tid >> 6, jg = (tid & 63)*4;
                        union { u64 q; u16 h[4]; } v; v.q = *(const u64*)(hbP + b*264 + jg);
                        float4 o; o.x=bf2f(v.h[0]); o.y=bf2f(v.h[1]); o.z=bf2f(v.h[2]); o.w=bf2f(v.h[3]);
                        *(float4*)(out + (size_t)(t-1)*5120 + (size_t)b*512 + off + jg) = o;
                    }
                    if (wu < 2) {   // store 1: tids 0-127 (idx 512..639)
                        const int idx = tid + 512;
                        const int b = idx >> 6, jg = (idx & 63)*4;
                        union { u64 q; u16 h[4]; } v; v.q = *(const u64*)(hbP + b*264 + jg);
                        float4 o; o.x=bf2f(v.h[0]); o.y=bf2f(v.h[1]); o.z=bf2f(v.h[2]); o.w=bf2f(v.h[3]);
                        *(float4*)(out + (size_t)(t-1)*5120 + (size_t)b*512 + off + jg) = o;
                    }
                }
            }
            // D: acc init (r,z x-parts from slot t%3) + 48 MFMAs over K=256
            const char* g0 = gb + (t%3)*32768;
            floatx4 acc[6];
#pragma unroll
            for (int g=0; g<2; ++g)
#pragma unroll
            for (int u=0; u<2; ++u) {
                const int col = g*256 + 32*w + 16*u + n16;
                const u64 gw = *(const u64*)(g0 + col*32 + quad*8);
#pragma unroll
                for (int r=0; r<4; ++r) acc[g*2+u][r] = bf2f((u16)(gw >> (16*r)));
            }
            acc[4] = (floatx4){0.f,0.f,0.f,0.f};
            acc[5] = (floatx4){0.f,0.f,0.f,0.f};
#pragma unroll
            for (int q=0; q<8; ++q) {
                short8 ah = *(const short8*)(hbP + n16*264 + q*32 + quad*8);
#pragma unroll
                for (int m=0; m<6; ++m)
                    acc[m] = __builtin_amdgcn_mfma_f32_16x16x32_bf16(ah, bh[m][q], acc[m], 0,0,0);
            }
            // E: nonlinearity (rcp-based), h(t) -> LDS slot (t+1)&1
            u16* hbN = hbuf + ((t+1)&1)*4224;
            const float* nxp = (const float*)(g0 + 16384);
#pragma unroll
            for (int u=0; u<2; ++u) {
                const int j = 32*w + 16*u + n16;
                const floatx4 nx4 = *(const floatx4*)(nxp + j*16 + quad*4);
#pragma unroll
                for (int r=0; r<4; ++r) {
                    const int b = quad*4 + r;
                    float rr = sigmoidf_(acc[u][r]);
                    float zz = sigmoidf_(acc[2+u][r]);
                    float nn = tanhf_(nx4[r] + rr*acc[4+u][r]);
                    float hp = bf2f(hbP[b*264 + j]);
                    float hn = nn + zz*(hp - nn);
                    hbN[b*264 + j] = f2bf(hn);
                }
            }
            // F: counted drain (steady formula; safe after slow poll because
            // poll drained all older ops => WVC(N) over-satisfied).
            if (t < 4 || t >= SEQ-5) {
                wait_vm0();
            } else if (s <= 4) {
                if (wu == 0)      { WVC(8); }
                else if (wu < 4)  { WVC(6); }
                else              { WVC(4); }
            } else {
                if (wu == 0)      { WVC(9); }
                else if (wu == 1) { WVC(8); }
                else              { WVC(6); }
            }
            lgkm_barrier();
        }
        // epilogue: h(511)/out(511) live in slot (512&1)=0
        const u16* hbL = hbuf;
        if (s<=4) {
            if (wu < 4) {
                const int b = tid & 15, k = (tid >> 4) & 15;
                char* hq = (char*)(hhb + (size_t)s*1048576 + (size_t)(SEQ-1)*2048);
                st16_sc1(hq + b*256 + k*16, *(const floatx4*)(hbL + b*264 + 8*k));
            }
        } else {
            const int off = (s==6)?256:0;
            {
                const int b = tid >> 6, jg = (tid & 63)*4;
                union { u64 q; u16 h[4]; } v; v.q = *(const u64*)(hbL + b*264 + jg);
                float4 o; o.x=bf2f(v.h[0]); o.y=bf2f(v.h[1]); o.z=bf2f(v.h[2]); o.w=bf2f(v.h[3]);
                *(float4*)(out + (size_t)(SEQ-1)*5120 + (size_t)b*512 + off + jg) = o;
            }
            if (wu < 2) {
                const int idx = tid + 512;
                const int b = idx >> 6, jg = (idx & 63)*4;
                union { u64 q; u16 h[4]; } v; v.q = *(const u64*)(hbL + b*264 + jg);
                float4 o; o.x=bf2f(v.h[0]); o.y=bf2f(v.h[1]); o.z=bf2f(v.h[2]); o.w=bf2f(v.h[3]);
                *(float4*)(out + (size_t)(SEQ-1)*5120 + (size_t)b*512 + off + jg) = o;
            }
        }
        wait_vm0(); lgkm_barrier();
        if (tid==0 && s<=4) {
            AST(htp + 508, 509u); AST(htp + 509, 510u);
            AST(htp + 510, 511u); AST(htp + 511, 512u);
        }
        return;
    }

    // ================= HELPERS: gates_x producers (6 WGs/stream) =================
    const int sh = (blk - 7) / 6;
    const int t0 = (blk - 7) % 6;

    const int layer = (sh==6)?5:sh, dir=(sh==6)?1:0;
    const float* wihp; int stride;
    if (layer==0){ wihp = wihl0 + (size_t)dir*768*128; stride=128; }
    else         { wihp = wihrest + ((size_t)((layer-1)*2+dir))*768*512; stride=512; }

    // 8 waves x 6 tiles: gate col = (w*6+i)*16 + n16
    short8 bxf[6][4];
#pragma unroll
    for (int i=0; i<6; ++i) {
        const int col = (w*6+i)*16 + n16;
#pragma unroll
        for (int q=0; q<4; ++q)
            bxf[i][q] = ld8f(wihp + (size_t)col*stride + q*32 + quad*8);
    }
    char* tb = (char*)smem_;               // 32 KB slot image
    const int bmA = (n16>9)?9:n16;
    const int lsrc = (sh==6)? 4 : (sh-1);
    u32* gtp_sh = tags + sh*32;

    // Software-pipelined publish: slot t's 16B sc1 stores issued at iter t;
    // tag published at iter t+6 after wait_vm0 + barrier (ack overlaps
    // the next iteration's load+MFMA). Ring audit at t+=6: writer needs
    // cparr >= t-24; consumer drained prior generation by F(t-33).
    int tprev = -1;
    for (int t = t0; t < SEQ; t += 6) {
        if (t >= 32) {   // ring-32 flow control vs consumer scan
            int gd=0;
            while ((int)ALD(cparr + sh) < t-24){ if(++gd>1000000) break; __builtin_amdgcn_s_sleep(8); }
        }
        if (tprev >= 0) {
            wait_vm0();            // own wave's slot-(tprev) stores acked
            __syncthreads();       // all waves acked (+ all tb readers done)
            if (tid==0) AST(gtp_sh + (tprev&31), (u32)(tprev+1));
        }
        short8 ax[4];
        if (sh == 0) {
            const float* xr = x + (size_t)t*1280 + (size_t)bmA*128;
#pragma unroll
            for (int q=0; q<4; ++q) ax[q] = ld8f(xr + q*32 + quad*8);
        } else {
            const int srct = (sh==6)? (SEQ-1-t) : t;
            int gd=0;
            while (ALD(tags + 256 + lsrc*512 + srct) != (u32)(srct+1)){ if(++gd>3000000) break; __builtin_amdgcn_s_sleep(4); }
            const u64* hq = (const u64*)(hhb + (size_t)lsrc*1048576 + (size_t)srct*2048);
#pragma unroll
            for (int q=0; q<4; ++q) {
                u64 a = ALD(hq + n16*32 + q*8 + quad*2);
                u64 b = ALD(hq + n16*32 + q*8 + quad*2 + 1);
                ax[q] = pk2(a, b);
            }
        }
        floatx4 acc[6];
#pragma unroll
        for (int i=0; i<6; ++i) acc[i] = (floatx4){0.f,0.f,0.f,0.f};
#pragma unroll
        for (int q=0; q<4; ++q)
#pragma unroll
            for (int i=0; i<6; ++i)
                acc[i] = __builtin_amdgcn_mfma_f32_16x16x32_bf16(ax[q], bxf[i][q], acc[i], 0,0,0);

        // slot image in LDS: rz bf16 [col<512][16], nx f32 [col-512][16]
        // (tb overwrite is safe: the tag barrier above drained all readers)
#pragma unroll
        for (int i=0; i<6; ++i) {
            const int col = (w*6+i)*16 + n16;
            if (col < 512) *(u64*)(tb + col*32 + quad*8) = pack4bf(acc[i]);
            else           *(floatx4*)(tb + 16384 + (col-512)*64 + quad*16) = acc[i];
        }
        __syncthreads();
        // publish 32KB slot: 4x 16B sc1 stores per thread
        char* gq = (char*)(gring + (size_t)(sh*32 + (t&31))*GSLOT_U64);
#pragma unroll
        for (int k=0;k<4;++k)
            st16_sc1(gq + tid*64 + k*16, *(const floatx4*)((const char*)tb + tid*64 + k*16));
        tprev = t;
    }
    wait_vm0(); __syncthreads();
    if (tid==0 && tprev>=0) AST(gtp_sh + (tprev&31), (u32)(tprev+1));
}

extern "C" void kernel_launch(void* const* d_in, const int* in_sizes, int n_in,
                              void* d_out, int out_size, void* d_ws, size_t ws_size,
                              hipStream_t stream) {
    (void)in_sizes; (void)n_in; (void)out_size; (void)ws_size;
    const float* x       = (const float*)d_in[0];
    const float* wihl0   = (const float*)d_in[1];
    const float* wihrest = (const float*)d_in[2];
    const float* whh     = (const float*)d_in[3];
    float* out = (float*)d_out;
    u64* gring = (u64*)d_ws;
    u16* hhb   = (u16*)((char*)d_ws + (size_t)GRING_U64*8);
    u32* tags  = (u32*)((char*)d_ws + TAGS_OFF_B);

    // No memset: 0xAAAAAAAA poison never equals a valid tag (1..512);
    // flow-control reads cast to int (poison negative => "not yet");
    // LDS tag mirrors hold stale-generation values => slow poll, no deadlock.
    gru_pipeline<<<dim3(49), dim3(512), 0, stream>>>(x, wihl0, wihrest, whh, out,
                                                     gring, hhb, tags);
}

// Round 9
// 3300.966 us; speedup vs baseline: 1.0448x; 1.0448x over previous
//
#include <hip/hip_runtime.h>
#include <stdint.h>

// Bidirectional GRU, 6 layers, H=256, S=512, B=10, fp32 in/out, bf16 MFMA.
// 7 scans + 21 helpers (r6-exact structure, 3371us verified base).
// THIS ROUND — LDS bank-conflict elimination via shared-image XOR swizzles:
//   Conflict map of r6 (SQ_LDS_BANK_CONFLICT=6.69M ~ 1870 cyc/scan-step):
//   - D rz acc-init u64 read (col*32+quad*8): 4-way (n16*8 mod 32 -> 4 slots)
//   - E nx 16B read (j*64+quad*16): 8-way (n16*16 mod 32 -> 2 slots)
//   Fixes (applied at BOTH helper-write and scan-read; DMA copies the byte
//   image verbatim so swizzle is transparent):
//   - rz: byte ^= ((col>>2)&3)<<3  -> 16 distinct dword residues, conflict-free
//   - nx: byte ^= ((j>>1)&3)<<4    -> 2-way (free per m136)
//   r8's burners dropped (suspected hang cause; r4 proved clock-forcing null).
//   HROW stays 264 (already 2-way for MFMA A-reads; r8 stride calc was wrong).
// Signature: SQ_LDS_BANK_CONFLICT 6.69M -> <=2.5M regardless of dur.

typedef short short8 __attribute__((ext_vector_type(8)));
typedef float floatx4 __attribute__((ext_vector_type(4)));
typedef unsigned long long u64;
typedef unsigned int u32;
typedef unsigned short u16;

#define SEQ 512

// ws: gring 7*32 slots x 32KB (rz bf16 swz + nx f32 swz) = 7.34MB
//     hh   scans 0..4 [t:512][b:16][ch:128] bf16 = 10.5MB
//     tags u32: gtag[7][32] @0 ; htag[5][512] @256 ; cparr[7] @2816
#define GSLOT_U64 4096
#define GRING_U64 (7 * 32 * GSLOT_U64)
#define HH_U16 (5 * 512 * 2048)
#define TAGS_OFF_B ((size_t)GRING_U64 * 8 + (size_t)HH_U16 * 2)

// swizzles (bijective within the 32KB slot image)
#define RZ_OFF(col, quad)  (((col)*32 + (quad)*8) ^ ((((col)>>2)&3)<<3))
#define NX_OFF(j, quad)    (16384 + (((j)*64 + (quad)*16) ^ ((((j)>>1)&3)<<4)))

__device__ __forceinline__ u16 f2bf(float f){ union{float f;u32 i;}v; v.f=f; u32 u=v.i; u += 0x7fffu + ((u>>16)&1u); return (u16)(u>>16); }
__device__ __forceinline__ float bf2f(u16 h){ union{u32 i;float f;}v; v.i=((u32)h)<<16; return v.f; }
__device__ __forceinline__ short8 ld8f(const float* p){
    float4 a=*(const float4*)p, b=*(const float4*)(p+4);
    short8 r; r[0]=(short)f2bf(a.x); r[1]=(short)f2bf(a.y); r[2]=(short)f2bf(a.z); r[3]=(short)f2bf(a.w);
    r[4]=(short)f2bf(b.x); r[5]=(short)f2bf(b.y); r[6]=(short)f2bf(b.z); r[7]=(short)f2bf(b.w); return r;
}
__device__ __forceinline__ short8 pk2(u64 a, u64 b){ union{u64 q[2]; short8 s;}v; v.q[0]=a; v.q[1]=b; return v.s; }
__device__ __forceinline__ u64 pack4bf(floatx4 a){
    return (u64)f2bf(a[0]) | ((u64)f2bf(a[1])<<16) | ((u64)f2bf(a[2])<<32) | ((u64)f2bf(a[3])<<48);
}
__device__ __forceinline__ float rcp_(float x){ float r; asm("v_rcp_f32 %0, %1" : "=v"(r) : "v"(x)); return r; }
__device__ __forceinline__ float sigmoidf_(float x){ return rcp_(1.0f + __expf(-x)); }
__device__ __forceinline__ float tanhf_(float x){ return 1.0f - 2.0f*rcp_(__expf(2.0f*x) + 1.0f); }

#define ALD(p)    __hip_atomic_load((p), __ATOMIC_RELAXED, __HIP_MEMORY_SCOPE_AGENT)
#define AST(p,v)  __hip_atomic_store((p),(v),__ATOMIC_RELAXED,__HIP_MEMORY_SCOPE_AGENT)
__device__ __forceinline__ void wait_vm0(){ asm volatile("s_waitcnt vmcnt(0)" ::: "memory"); }
#define WVC(n) asm volatile("s_waitcnt vmcnt(" #n ")" ::: "memory")
__device__ __forceinline__ void lgkm_barrier(){ asm volatile("s_waitcnt lgkmcnt(0)\n\ts_barrier" ::: "memory"); }

__device__ __forceinline__ void st16_sc1(void* p, floatx4 v){
    asm volatile("global_store_dwordx4 %0, %1, off sc1" :: "v"(p), "v"(v) : "memory");
}
__device__ __forceinline__ void dma16(const void* g, void* l) {
    __builtin_amdgcn_global_load_lds(
        reinterpret_cast<const __attribute__((address_space(1))) unsigned int*>(
            (uintptr_t)g),
        reinterpret_cast<__attribute__((address_space(3))) unsigned int*>(
            (uintptr_t)l), 16, 0, 16);
}
__device__ __forceinline__ void dma4(const void* g, void* l) {
    __builtin_amdgcn_global_load_lds(
        reinterpret_cast<const __attribute__((address_space(1))) unsigned int*>(
            (uintptr_t)g),
        reinterpret_cast<__attribute__((address_space(3))) unsigned int*>(
            (uintptr_t)l), 4, 0, 16);
}

__global__ __launch_bounds__(512, 2)
void gru_pipeline(const float* __restrict__ x,
                  const float* __restrict__ wihl0,
                  const float* __restrict__ wihrest,
                  const float* __restrict__ whh,
                  float* __restrict__ out,
                  u64* __restrict__ gring,
                  u16* __restrict__ hhb,
                  u32* __restrict__ tags)
{
    __shared__ u64 smem_[14404];   // 115,232 B: gbuf 3x32768 + hbuf 16,896 + tagmir 16
    const int blk  = blockIdx.x;
    const int tid  = threadIdx.x;
    const int w    = tid >> 6;
    const int lane = tid & 63;
    const int n16  = lane & 15;
    const int quad = lane >> 4;
    u32* cparr = tags + 2816;

    if (blk < 7) {
        // ================= SCAN: one 512-thread WG per scan =================
        const int s = blk;
        const int wu = __builtin_amdgcn_readfirstlane(tid) >> 6;   // wave idx, SGPR
        const int layer = (s==6)?5:s, dir=(s==6)?1:0;
        const float* whhp = whh + ((size_t)(layer*2+dir))*768*256;

        short8 bh[6][8];
#pragma unroll
        for (int g=0; g<3; ++g)
#pragma unroll
        for (int u=0; u<2; ++u) {
            const int row = g*256 + 32*w + 16*u + n16;
#pragma unroll
            for (int q=0; q<8; ++q)
                bh[g*2+u][q] = ld8f(whhp + (size_t)row*256 + q*32 + quad*8);
        }

        char* gb   = (char*)smem_;                      // gate slots: [3][32768 B]
        u16*  hbuf = (u16*)(gb + 98304);                // [2][16][264] bf16
        u32*  tagmir = (u32*)((char*)smem_ + 115200);   // [4] gtag mirror ring
        for (int i=tid; i<8448; i+=512) hbuf[i] = 0;    // h(-1)=0 (both slots)

        u32* gtp = tags + s*32;
        u32* htp = tags + 256 + s*512;

        // prologue: stage gates(0), gates(1); mirror tags for slots 2,3
        {
            int gd=0;
            while (ALD(gtp + 0) != 1u){ if(++gd>3000000) break; __builtin_amdgcn_s_sleep(2); }
            const char* sg = (const char*)(gring + (size_t)(s*32)*GSLOT_U64);
#pragma unroll
            for (int r=0; r<4; ++r) dma16(sg + (r*512+tid)*16, gb + (r*512+tid)*16);
            gd=0;
            while (ALD(gtp + 1) != 2u){ if(++gd>3000000) break; __builtin_amdgcn_s_sleep(2); }
            sg = (const char*)(gring + (size_t)(s*32 + 1)*GSLOT_U64);
#pragma unroll
            for (int r=0; r<4; ++r) dma16(sg + (r*512+tid)*16, gb + 32768 + (r*512+tid)*16);
            if (tid==0) { dma4(gtp + 2, tagmir + 2); dma4(gtp + 3, tagmir + 3); }
            wait_vm0(); lgkm_barrier();
        }

        for (int t=0; t<SEQ; ++t) {
            const u16* hbP = hbuf + (t&1)*4224;
            // A (post-barrier): tags, mirror check, tagdma(t+4), dma(t+2).
            if (wu == 0) {
                if ((t&3)==0) AST(cparr + s, (u32)(t+1));
                if (s<=4 && t>=4) AST(htp + (t-4), (u32)(t-3));
            }
            if (t+2 < SEQ) {
                if (tagmir[(t+2)&3] != (u32)(t+3)) {
                    int gd=0;
                    while (ALD(gtp + ((t+2)&31)) != (u32)(t+3)){ if(++gd>3000000) break; __builtin_amdgcn_s_sleep(1); }
                }
                if (wu==0 && lane==0 && t+4 < SEQ)
                    dma4(gtp + ((t+4)&31), tagmir + ((t+4)&3));
                const char* sg = (const char*)(gring + (size_t)(s*32 + ((t+2)&31))*GSLOT_U64);
                char* dg = gb + ((t+2)%3)*32768;
#pragma unroll
                for (int r=0; r<4; ++r) dma16(sg + (r*512+tid)*16, dg + (r*512+tid)*16);
            }

            // B: publish h(t-1) / out(t-1) from LDS slot t&1
            if (t >= 1) {
                if (s<=4) {
                    if (wu < 4) {
                        const int b = tid & 15, k = (tid >> 4) & 15;
                        char* hq = (char*)(hhb + (size_t)s*1048576 + (size_t)(t-1)*2048);
                        st16_sc1(hq + b*256 + k*16, *(const floatx4*)(hbP + b*264 + 8*k));
                    }
                } else {
                    const int off = (s==6)?256:0;
                    {
                        const int b = tid >> 6, jg = (tid & 63)*4;
                        union { u64 q; u16 h[4]; } v; v.q = *(const u64*)(hbP + b*264 + jg);
                        float4 o; o.x=bf2f(v.h[0]); o.y=bf2f(v.h[1]); o.z=bf2f(v.h[2]); o.w=bf2f(v.h[3]);
                        *(float4*)(out + (size_t)(t-1)*5120 + (size_t)b*512 + off + jg) = o;
                    }
                    if (wu < 2) {
                        const int idx = tid + 512;
                        const int b = idx >> 6, jg = (idx & 63)*4;
                        union { u64 q; u16 h[4]; } v; v.q = *(const u64*)(hbP + b*264 + jg);
                        float4 o; o.x=bf2f(v.h[0]); o.y=bf2f(v.h[1]); o.z=bf2f(v.h[2]); o.w=bf2f(v.h[3]);
                        *(float4*)(out + (size_t)(t-1)*5120 + (size_t)b*512 + off + jg) = o;
                    }
                }
            }
            // D: acc init (rz x-parts, SWIZZLED read) + 48 MFMAs over K=256
            const char* g0 = gb + (t%3)*32768;
            floatx4 acc[6];
#pragma unroll
            for (int g=0; g<2; ++g)
#pragma unroll
            for (int u=0; u<2; ++u) {
                const int col = g*256 + 32*w + 16*u + n16;
                const u64 gw = *(const u64*)(g0 + RZ_OFF(col, quad));
#pragma unroll
                for (int r=0; r<4; ++r) acc[g*2+u][r] = bf2f((u16)(gw >> (16*r)));
            }
            acc[4] = (floatx4){0.f,0.f,0.f,0.f};
            acc[5] = (floatx4){0.f,0.f,0.f,0.f};
#pragma unroll
            for (int q=0; q<8; ++q) {
                short8 ah = *(const short8*)(hbP + n16*264 + q*32 + quad*8);
#pragma unroll
                for (int m=0; m<6; ++m)
                    acc[m] = __builtin_amdgcn_mfma_f32_16x16x32_bf16(ah, bh[m][q], acc[m], 0,0,0);
            }
            // E: nonlinearity (nx SWIZZLED read), h(t) -> LDS slot (t+1)&1
            u16* hbN = hbuf + ((t+1)&1)*4224;
#pragma unroll
            for (int u=0; u<2; ++u) {
                const int j = 32*w + 16*u + n16;
                const floatx4 nx4 = *(const floatx4*)(g0 + NX_OFF(j, quad));
#pragma unroll
                for (int r=0; r<4; ++r) {
                    const int b = quad*4 + r;
                    float rr = sigmoidf_(acc[u][r]);
                    float zz = sigmoidf_(acc[2+u][r]);
                    float nn = tanhf_(nx4[r] + rr*acc[4+u][r]);
                    float hp = bf2f(hbP[b*264 + j]);
                    float hn = nn + zz*(hp - nn);
                    hbN[b*264 + j] = f2bf(hn);
                }
            }
            // F: counted drain (r6-exact; safe after slow poll: over-satisfied)
            if (t < 4 || t >= SEQ-5) {
                wait_vm0();
            } else if (s <= 4) {
                if (wu == 0)      { WVC(8); }
                else if (wu < 4)  { WVC(6); }
                else              { WVC(4); }
            } else {
                if (wu == 0)      { WVC(9); }
                else if (wu == 1) { WVC(8); }
                else              { WVC(6); }
            }
            lgkm_barrier();
        }
        // epilogue: h(511)/out(511) live in slot (512&1)=0
        const u16* hbL = hbuf;
        if (s<=4) {
            if (wu < 4) {
                const int b = tid & 15, k = (tid >> 4) & 15;
                char* hq = (char*)(hhb + (size_t)s*1048576 + (size_t)(SEQ-1)*2048);
                st16_sc1(hq + b*256 + k*16, *(const floatx4*)(hbL + b*264 + 8*k));
            }
        } else {
            const int off = (s==6)?256:0;
            {
                const int b = tid >> 6, jg = (tid & 63)*4;
                union { u64 q; u16 h[4]; } v; v.q = *(const u64*)(hbL + b*264 + jg);
                float4 o; o.x=bf2f(v.h[0]); o.y=bf2f(v.h[1]); o.z=bf2f(v.h[2]); o.w=bf2f(v.h[3]);
                *(float4*)(out + (size_t)(SEQ-1)*5120 + (size_t)b*512 + off + jg) = o;
            }
            if (wu < 2) {
                const int idx = tid + 512;
                const int b = idx >> 6, jg = (idx & 63)*4;
                union { u64 q; u16 h[4]; } v; v.q = *(const u64*)(hbL + b*264 + jg);
                float4 o; o.x=bf2f(v.h[0]); o.y=bf2f(v.h[1]); o.z=bf2f(v.h[2]); o.w=bf2f(v.h[3]);
                *(float4*)(out + (size_t)(SEQ-1)*5120 + (size_t)b*512 + off + jg) = o;
            }
        }
        wait_vm0(); lgkm_barrier();
        if (tid==0 && s<=4) {
            AST(htp + 508, 509u); AST(htp + 509, 510u);
            AST(htp + 510, 511u); AST(htp + 511, 512u);
        }
        return;
    }

    // ================= HELPERS: gates_x producers (3 WGs/stream) =================
    int sh, t0;
    if (blk < 10)      { sh = 0;               t0 = blk - 7;      }
    else if (blk < 25) { sh = 1 + (blk-10)/3;  t0 = (blk-10)%3;   }
    else               { sh = 6;               t0 = blk - 25;     }

    const int layer = (sh==6)?5:sh, dir=(sh==6)?1:0;
    const float* wihp; int stride;
    if (layer==0){ wihp = wihl0 + (size_t)dir*768*128; stride=128; }
    else         { wihp = wihrest + ((size_t)((layer-1)*2+dir))*768*512; stride=512; }

    short8 bxf[6][4];
#pragma unroll
    for (int i=0; i<6; ++i) {
        const int col = (w*6+i)*16 + n16;
#pragma unroll
        for (int q=0; q<4; ++q)
            bxf[i][q] = ld8f(wihp + (size_t)col*stride + q*32 + quad*8);
    }
    char* tb = (char*)smem_;               // 32 KB slot image
    const int bmA = (n16>9)?9:n16;
    const int lsrc = (sh==6)? 4 : (sh-1);
    u32* gtp_sh = tags + sh*32;

    // Software-pipelined publish (r6-exact): stores at iter t, tag at t+3.
    int tprev = -1;
    for (int t = t0; t < SEQ; t += 3) {
        if (t >= 32) {
            int gd=0;
            while ((int)ALD(cparr + sh) < t-24){ if(++gd>1000000) break; __builtin_amdgcn_s_sleep(8); }
        }
        if (tprev >= 0) {
            wait_vm0();
            __syncthreads();
            if (tid==0) AST(gtp_sh + (tprev&31), (u32)(tprev+1));
        }
        short8 ax[4];
        if (sh == 0) {
            const float* xr = x + (size_t)t*1280 + (size_t)bmA*128;
#pragma unroll
            for (int q=0; q<4; ++q) ax[q] = ld8f(xr + q*32 + quad*8);
        } else {
            const int srct = (sh==6)? (SEQ-1-t) : t;
            int gd=0;
            while (ALD(tags + 256 + lsrc*512 + srct) != (u32)(srct+1)){ if(++gd>3000000) break; __builtin_amdgcn_s_sleep(4); }
            const u64* hq = (const u64*)(hhb + (size_t)lsrc*1048576 + (size_t)srct*2048);
#pragma unroll
            for (int q=0; q<4; ++q) {
                u64 a = ALD(hq + n16*32 + q*8 + quad*2);
                u64 b = ALD(hq + n16*32 + q*8 + quad*2 + 1);
                ax[q] = pk2(a, b);
            }
        }
        floatx4 acc[6];
#pragma unroll
        for (int i=0; i<6; ++i) acc[i] = (floatx4){0.f,0.f,0.f,0.f};
#pragma unroll
        for (int q=0; q<4; ++q)
#pragma unroll
            for (int i=0; i<6; ++i)
                acc[i] = __builtin_amdgcn_mfma_f32_16x16x32_bf16(ax[q], bxf[i][q], acc[i], 0,0,0);

        // slot image (SWIZZLED): rz bf16 + nx f32; matches scan-side reads
#pragma unroll
        for (int i=0; i<6; ++i) {
            const int col = (w*6+i)*16 + n16;
            if (col < 512) *(u64*)(tb + RZ_OFF(col, quad)) = pack4bf(acc[i]);
            else           *(floatx4*)(tb + NX_OFF(col-512, quad)) = acc[i];
        }
        __syncthreads();
        char* gq = (char*)(gring + (size_t)(sh*32 + (t&31))*GSLOT_U64);
#pragma unroll
        for (int k=0;k<4;++k)
            st16_sc1(gq + tid*64 + k*16, *(const floatx4*)((const char*)tb + tid*64 + k*16));
        tprev = t;
    }
    wait_vm0(); __syncthreads();
    if (tid==0 && tprev>=0) AST(gtp_sh + (tprev&31), (u32)(tprev+1));
}

extern "C" void kernel_launch(void* const* d_in, const int* in_sizes, int n_in,
                              void* d_out, int out_size, void* d_ws, size_t ws_size,
                              hipStream_t stream) {
    (void)in_sizes; (void)n_in; (void)out_size; (void)ws_size;
    const float* x       = (const float*)d_in[0];
    const float* wihl0   = (const float*)d_in[1];
    const float* wihrest = (const float*)d_in[2];
    const float* whh     = (const float*)d_in[3];
    float* out = (float*)d_out;
    u64* gring = (u64*)d_ws;
    u16* hhb   = (u16*)((char*)d_ws + (size_t)GRING_U64*8);
    u32* tags  = (u32*)((char*)d_ws + TAGS_OFF_B);

    // No memset: 0xAAAAAAAA poison never equals a valid tag (1..512);
    // flow-control reads cast to int; LDS tag mirrors stale => slow poll.
    gru_pipeline<<<dim3(28), dim3(512), 0, stream>>>(x, wihl0, wihrest, whh, out,
                                                     gring, hhb, tags);
}

// Round 10
// 3039.088 us; speedup vs baseline: 1.1349x; 1.0862x over previous
//
#include <hip/hip_runtime.h>
#include <stdint.h>

// Bidirectional GRU, 6 layers, H=256, S=512, B=10, fp32 in/out, bf16 MFMA.
// 7 scans + 21 helpers (r9-exact helper side, swizzled slot image).
// THIS ROUND — wave ROLE-SPLIT to decouple store-ack drains from the gate
// deadline (vmcnt retires IN ORDER per wave, so any store interleaved with
// the gate DMAs inherits the DMA's 1.9-step drain deadline; measured r5/r6/r9
// all equilibrate at step ~= ack_latency/1.35 ~= 3.2us):
//   - staging waves 0-3: 8x dma16/wave (+w0 dma4 tag mirror). WVC(9)/WVC(8)
//     at F enforce ONLY the gate deadline (stream has no stores).
//   - store waves 4-7: h-store (s<=4) / out-stores (s5/6) + tags; NO F-phase
//     vmcnt wait -> acks float ~8 steps (HW cap 63 outstanding >> 2/step).
//     htag(t-4) data-before-tag: wave4 WVC(4) immediately before the AST
//     (h-store(t-4) is >=5th-newest in wave4's stream at A(t); t<4 edge
//     full-drains). cparr needs no ordering.
//   - edges t<4, t>=SEQ-5: wait_vm0 all waves (covers warm-up/drain).
// D/E phases (MFMA + nonlinearity) unchanged; LDS swizzles from r9 kept.

typedef short short8 __attribute__((ext_vector_type(8)));
typedef float floatx4 __attribute__((ext_vector_type(4)));
typedef unsigned long long u64;
typedef unsigned int u32;
typedef unsigned short u16;

#define SEQ 512

// ws: gring 7*32 slots x 32KB (rz bf16 swz + nx f32 swz) = 7.34MB
//     hh   scans 0..4 [t:512][b:16][ch:128] bf16 = 10.5MB
//     tags u32: gtag[7][32] @0 ; htag[5][512] @256 ; cparr[7] @2816
#define GSLOT_U64 4096
#define GRING_U64 (7 * 32 * GSLOT_U64)
#define HH_U16 (5 * 512 * 2048)
#define TAGS_OFF_B ((size_t)GRING_U64 * 8 + (size_t)HH_U16 * 2)

// swizzles (bijective within the 32KB slot image; r9-verified)
#define RZ_OFF(col, quad)  (((col)*32 + (quad)*8) ^ ((((col)>>2)&3)<<3))
#define NX_OFF(j, quad)    (16384 + (((j)*64 + (quad)*16) ^ ((((j)>>1)&3)<<4)))

__device__ __forceinline__ u16 f2bf(float f){ union{float f;u32 i;}v; v.f=f; u32 u=v.i; u += 0x7fffu + ((u>>16)&1u); return (u16)(u>>16); }
__device__ __forceinline__ float bf2f(u16 h){ union{u32 i;float f;}v; v.i=((u32)h)<<16; return v.f; }
__device__ __forceinline__ short8 ld8f(const float* p){
    float4 a=*(const float4*)p, b=*(const float4*)(p+4);
    short8 r; r[0]=(short)f2bf(a.x); r[1]=(short)f2bf(a.y); r[2]=(short)f2bf(a.z); r[3]=(short)f2bf(a.w);
    r[4]=(short)f2bf(b.x); r[5]=(short)f2bf(b.y); r[6]=(short)f2bf(b.z); r[7]=(short)f2bf(b.w); return r;
}
__device__ __forceinline__ short8 pk2(u64 a, u64 b){ union{u64 q[2]; short8 s;}v; v.q[0]=a; v.q[1]=b; return v.s; }
__device__ __forceinline__ u64 pack4bf(floatx4 a){
    return (u64)f2bf(a[0]) | ((u64)f2bf(a[1])<<16) | ((u64)f2bf(a[2])<<32) | ((u64)f2bf(a[3])<<48);
}
__device__ __forceinline__ float rcp_(float x){ float r; asm("v_rcp_f32 %0, %1" : "=v"(r) : "v"(x)); return r; }
__device__ __forceinline__ float sigmoidf_(float x){ return rcp_(1.0f + __expf(-x)); }
__device__ __forceinline__ float tanhf_(float x){ return 1.0f - 2.0f*rcp_(__expf(2.0f*x) + 1.0f); }

#define ALD(p)    __hip_atomic_load((p), __ATOMIC_RELAXED, __HIP_MEMORY_SCOPE_AGENT)
#define AST(p,v)  __hip_atomic_store((p),(v),__ATOMIC_RELAXED,__HIP_MEMORY_SCOPE_AGENT)
__device__ __forceinline__ void wait_vm0(){ asm volatile("s_waitcnt vmcnt(0)" ::: "memory"); }
#define WVC(n) asm volatile("s_waitcnt vmcnt(" #n ")" ::: "memory")
__device__ __forceinline__ void lgkm_barrier(){ asm volatile("s_waitcnt lgkmcnt(0)\n\ts_barrier" ::: "memory"); }

__device__ __forceinline__ void st16_sc1(void* p, floatx4 v){
    asm volatile("global_store_dwordx4 %0, %1, off sc1" :: "v"(p), "v"(v) : "memory");
}
__device__ __forceinline__ void dma16(const void* g, void* l) {
    __builtin_amdgcn_global_load_lds(
        reinterpret_cast<const __attribute__((address_space(1))) unsigned int*>(
            (uintptr_t)g),
        reinterpret_cast<__attribute__((address_space(3))) unsigned int*>(
            (uintptr_t)l), 16, 0, 16);
}
__device__ __forceinline__ void dma4(const void* g, void* l) {
    __builtin_amdgcn_global_load_lds(
        reinterpret_cast<const __attribute__((address_space(1))) unsigned int*>(
            (uintptr_t)g),
        reinterpret_cast<__attribute__((address_space(3))) unsigned int*>(
            (uintptr_t)l), 4, 0, 16);
}

__global__ __launch_bounds__(512, 2)
void gru_pipeline(const float* __restrict__ x,
                  const float* __restrict__ wihl0,
                  const float* __restrict__ wihrest,
                  const float* __restrict__ whh,
                  float* __restrict__ out,
                  u64* __restrict__ gring,
                  u16* __restrict__ hhb,
                  u32* __restrict__ tags)
{
    __shared__ u64 smem_[14404];   // 115,232 B: gbuf 3x32768 + hbuf 16,896 + tagmir 16
    const int blk  = blockIdx.x;
    const int tid  = threadIdx.x;
    const int w    = tid >> 6;
    const int lane = tid & 63;
    const int n16  = lane & 15;
    const int quad = lane >> 4;
    u32* cparr = tags + 2816;

    if (blk < 7) {
        // ================= SCAN: one 512-thread WG per scan =================
        const int s = blk;
        const int wu = __builtin_amdgcn_readfirstlane(tid) >> 6;   // wave idx, SGPR
        const int layer = (s==6)?5:s, dir=(s==6)?1:0;
        const float* whhp = whh + ((size_t)(layer*2+dir))*768*256;

        short8 bh[6][8];
#pragma unroll
        for (int g=0; g<3; ++g)
#pragma unroll
        for (int u=0; u<2; ++u) {
            const int row = g*256 + 32*w + 16*u + n16;
#pragma unroll
            for (int q=0; q<8; ++q)
                bh[g*2+u][q] = ld8f(whhp + (size_t)row*256 + q*32 + quad*8);
        }

        char* gb   = (char*)smem_;                      // gate slots: [3][32768 B]
        u16*  hbuf = (u16*)(gb + 98304);                // [2][16][264] bf16
        u32*  tagmir = (u32*)((char*)smem_ + 115200);   // [4] gtag mirror ring
        for (int i=tid; i<8448; i+=512) hbuf[i] = 0;    // h(-1)=0 (both slots)

        u32* gtp = tags + s*32;
        u32* htp = tags + 256 + s*512;

        // prologue: staging waves (tid<256) stage gates(0),(1); mirror 2,3
        {
            int gd=0;
            while (ALD(gtp + 0) != 1u){ if(++gd>3000000) break; __builtin_amdgcn_s_sleep(2); }
            if (tid < 256) {
                const char* sg = (const char*)(gring + (size_t)(s*32)*GSLOT_U64);
#pragma unroll
                for (int r=0; r<8; ++r) dma16(sg + (r*256+tid)*16, gb + (r*256+tid)*16);
            }
            gd=0;
            while (ALD(gtp + 1) != 2u){ if(++gd>3000000) break; __builtin_amdgcn_s_sleep(2); }
            if (tid < 256) {
                const char* sg = (const char*)(gring + (size_t)(s*32 + 1)*GSLOT_U64);
#pragma unroll
                for (int r=0; r<8; ++r) dma16(sg + (r*256+tid)*16, gb + 32768 + (r*256+tid)*16);
            }
            if (tid==0) { dma4(gtp + 2, tagmir + 2); dma4(gtp + 3, tagmir + 3); }
            wait_vm0(); lgkm_barrier();
        }

        for (int t=0; t<SEQ; ++t) {
            const u16* hbP = hbuf + (t&1)*4224;
            // A: staging waves (0-3): mirror check + dma4(t+4) + dma16(t+2).
            if (t+2 < SEQ && wu < 4) {
                if (tagmir[(t+2)&3] != (u32)(t+3)) {    // rare: warm-up/helper-late
                    int gd=0;
                    while (ALD(gtp + ((t+2)&31)) != (u32)(t+3)){ if(++gd>3000000) break; __builtin_amdgcn_s_sleep(1); }
                }
                if (wu==0 && lane==0 && t+4 < SEQ)
                    dma4(gtp + ((t+4)&31), tagmir + ((t+4)&3));
                const char* sg = (const char*)(gring + (size_t)(s*32 + ((t+2)&31))*GSLOT_U64);
                char* dg = gb + ((t+2)%3)*32768;
#pragma unroll
                for (int r=0; r<8; ++r) dma16(sg + (r*256+tid)*16, dg + (r*256+tid)*16);
            }
            // A': wave 4 owns the tags. htag(t-4) needs h-store(t-4) retired:
            // it is >=5th-newest in wave4's store-only stream => WVC(4).
            if (wu == 4) {
                if (s<=4 && t>=4) { WVC(4); AST(htp + (t-4), (u32)(t-3)); }
                if ((t&3)==0) AST(cparr + s, (u32)(t+1));
            }

            // B: store waves (4-7) publish h(t-1) / out(t-1) from slot t&1
            if (t >= 1 && wu >= 4) {
                if (s<=4) {
                    const int idx = tid - 256;          // 0..255
                    const int b = idx & 15, k = (idx >> 4) & 15;
                    char* hq = (char*)(hhb + (size_t)s*1048576 + (size_t)(t-1)*2048);
                    st16_sc1(hq + b*256 + k*16, *(const floatx4*)(hbP + b*264 + 8*k));
                } else {
                    const int off = (s==6)?256:0;
#pragma unroll
                    for (int k=0;k<3;++k) {
                        const int idx = (tid-256) + 256*k;   // 0..767, need <640
                        if (idx < 640) {
                            const int b = idx >> 6, jg = (idx & 63)*4;
                            union { u64 q; u16 h[4]; } v; v.q = *(const u64*)(hbP + b*264 + jg);
                            float4 o; o.x=bf2f(v.h[0]); o.y=bf2f(v.h[1]); o.z=bf2f(v.h[2]); o.w=bf2f(v.h[3]);
                            *(float4*)(out + (size_t)(t-1)*5120 + (size_t)b*512 + off + jg) = o;
                        }
                    }
                }
            }
            // D: acc init (rz swizzled) + 48 MFMAs over K=256 (all waves)
            const char* g0 = gb + (t%3)*32768;
            floatx4 acc[6];
#pragma unroll
            for (int g=0; g<2; ++g)
#pragma unroll
            for (int u=0; u<2; ++u) {
                const int col = g*256 + 32*w + 16*u + n16;
                const u64 gw = *(const u64*)(g0 + RZ_OFF(col, quad));
#pragma unroll
                for (int r=0; r<4; ++r) acc[g*2+u][r] = bf2f((u16)(gw >> (16*r)));
            }
            acc[4] = (floatx4){0.f,0.f,0.f,0.f};
            acc[5] = (floatx4){0.f,0.f,0.f,0.f};
#pragma unroll
            for (int q=0; q<8; ++q) {
                short8 ah = *(const short8*)(hbP + n16*264 + q*32 + quad*8);
#pragma unroll
                for (int m=0; m<6; ++m)
                    acc[m] = __builtin_amdgcn_mfma_f32_16x16x32_bf16(ah, bh[m][q], acc[m], 0,0,0);
            }
            // E: nonlinearity (nx swizzled), h(t) -> LDS slot (t+1)&1
            u16* hbN = hbuf + ((t+1)&1)*4224;
#pragma unroll
            for (int u=0; u<2; ++u) {
                const int j = 32*w + 16*u + n16;
                const floatx4 nx4 = *(const floatx4*)(g0 + NX_OFF(j, quad));
#pragma unroll
                for (int r=0; r<4; ++r) {
                    const int b = quad*4 + r;
                    float rr = sigmoidf_(acc[u][r]);
                    float zz = sigmoidf_(acc[2+u][r]);
                    float nn = tanhf_(nx4[r] + rr*acc[4+u][r]);
                    float hp = bf2f(hbP[b*264 + j]);
                    float hn = nn + zz*(hp - nn);
                    hbN[b*264 + j] = f2bf(hn);
                }
            }
            // F: staging waves enforce the gate deadline; store waves float.
            // w0/step = dma4+8dma16 = 9 ops; w1-3 = 8. dma16(t+1) (issued
            // A(t-1)) has exactly next-step's 9/8 ops after it -> WVC(9)/(8).
            if (t < 4 || t >= SEQ-5) {
                wait_vm0();
            } else if (wu == 0) {
                WVC(9);
            } else if (wu < 4) {
                WVC(8);
            }                               // wu>=4: no vmcnt wait
            lgkm_barrier();
        }
        // epilogue: h(511)/out(511) live in slot (512&1)=0
        const u16* hbL = hbuf;
        if (wu >= 4) {
            if (s<=4) {
                const int idx = tid - 256;
                const int b = idx & 15, k = (idx >> 4) & 15;
                char* hq = (char*)(hhb + (size_t)s*1048576 + (size_t)(SEQ-1)*2048);
                st16_sc1(hq + b*256 + k*16, *(const floatx4*)(hbL + b*264 + 8*k));
            } else {
                const int off = (s==6)?256:0;
#pragma unroll
                for (int k=0;k<3;++k) {
                    const int idx = (tid-256) + 256*k;
                    if (idx < 640) {
                        const int b = idx >> 6, jg = (idx & 63)*4;
                        union { u64 q; u16 h[4]; } v; v.q = *(const u64*)(hbL + b*264 + jg);
                        float4 o; o.x=bf2f(v.h[0]); o.y=bf2f(v.h[1]); o.z=bf2f(v.h[2]); o.w=bf2f(v.h[3]);
                        *(float4*)(out + (size_t)(SEQ-1)*5120 + (size_t)b*512 + off + jg) = o;
                    }
                }
            }
        }
        wait_vm0(); lgkm_barrier();
        if (tid==0 && s<=4) {
            AST(htp + 508, 509u); AST(htp + 509, 510u);
            AST(htp + 510, 511u); AST(htp + 511, 512u);
        }
        return;
    }

    // ================= HELPERS: gates_x producers (3 WGs/stream, r9-exact) ========
    int sh, t0;
    if (blk < 10)      { sh = 0;               t0 = blk - 7;      }
    else if (blk < 25) { sh = 1 + (blk-10)/3;  t0 = (blk-10)%3;   }
    else               { sh = 6;               t0 = blk - 25;     }

    const int layer = (sh==6)?5:sh, dir=(sh==6)?1:0;
    const float* wihp; int stride;
    if (layer==0){ wihp = wihl0 + (size_t)dir*768*128; stride=128; }
    else         { wihp = wihrest + ((size_t)((layer-1)*2+dir))*768*512; stride=512; }

    short8 bxf[6][4];
#pragma unroll
    for (int i=0; i<6; ++i) {
        const int col = (w*6+i)*16 + n16;
#pragma unroll
        for (int q=0; q<4; ++q)
            bxf[i][q] = ld8f(wihp + (size_t)col*stride + q*32 + quad*8);
    }
    char* tb = (char*)smem_;               // 32 KB slot image
    const int bmA = (n16>9)?9:n16;
    const int lsrc = (sh==6)? 4 : (sh-1);
    u32* gtp_sh = tags + sh*32;

    // Software-pipelined publish: stores at iter t, tag at t+3.
    int tprev = -1;
    for (int t = t0; t < SEQ; t += 3) {
        if (t >= 32) {
            int gd=0;
            while ((int)ALD(cparr + sh) < t-24){ if(++gd>1000000) break; __builtin_amdgcn_s_sleep(8); }
        }
        if (tprev >= 0) {
            wait_vm0();
            __syncthreads();
            if (tid==0) AST(gtp_sh + (tprev&31), (u32)(tprev+1));
        }
        short8 ax[4];
        if (sh == 0) {
            const float* xr = x + (size_t)t*1280 + (size_t)bmA*128;
#pragma unroll
            for (int q=0; q<4; ++q) ax[q] = ld8f(xr + q*32 + quad*8);
        } else {
            const int srct = (sh==6)? (SEQ-1-t) : t;
            int gd=0;
            while (ALD(tags + 256 + lsrc*512 + srct) != (u32)(srct+1)){ if(++gd>3000000) break; __builtin_amdgcn_s_sleep(4); }
            const u64* hq = (const u64*)(hhb + (size_t)lsrc*1048576 + (size_t)srct*2048);
#pragma unroll
            for (int q=0; q<4; ++q) {
                u64 a = ALD(hq + n16*32 + q*8 + quad*2);
                u64 b = ALD(hq + n16*32 + q*8 + quad*2 + 1);
                ax[q] = pk2(a, b);
            }
        }
        floatx4 acc[6];
#pragma unroll
        for (int i=0; i<6; ++i) acc[i] = (floatx4){0.f,0.f,0.f,0.f};
#pragma unroll
        for (int q=0; q<4; ++q)
#pragma unroll
            for (int i=0; i<6; ++i)
                acc[i] = __builtin_amdgcn_mfma_f32_16x16x32_bf16(ax[q], bxf[i][q], acc[i], 0,0,0);

        // slot image (SWIZZLED): rz bf16 + nx f32; matches scan-side reads
#pragma unroll
        for (int i=0; i<6; ++i) {
            const int col = (w*6+i)*16 + n16;
            if (col < 512) *(u64*)(tb + RZ_OFF(col, quad)) = pack4bf(acc[i]);
            else           *(floatx4*)(tb + NX_OFF(col-512, quad)) = acc[i];
        }
        __syncthreads();
        char* gq = (char*)(gring + (size_t)(sh*32 + (t&31))*GSLOT_U64);
#pragma unroll
        for (int k=0;k<4;++k)
            st16_sc1(gq + tid*64 + k*16, *(const floatx4*)((const char*)tb + tid*64 + k*16));
        tprev = t;
    }
    wait_vm0(); __syncthreads();
    if (tid==0 && tprev>=0) AST(gtp_sh + (tprev&31), (u32)(tprev+1));
}

extern "C" void kernel_launch(void* const* d_in, const int* in_sizes, int n_in,
                              void* d_out, int out_size, void* d_ws, size_t ws_size,
                              hipStream_t stream) {
    (void)in_sizes; (void)n_in; (void)out_size; (void)ws_size;
    const float* x       = (const float*)d_in[0];
    const float* wihl0   = (const float*)d_in[1];
    const float* wihrest = (const float*)d_in[2];
    const float* whh     = (const float*)d_in[3];
    float* out = (float*)d_out;
    u64* gring = (u64*)d_ws;
    u16* hhb   = (u16*)((char*)d_ws + (size_t)GRING_U64*8);
    u32* tags  = (u32*)((char*)d_ws + TAGS_OFF_B);

    // No memset: 0xAAAAAAAA poison never equals a valid tag (1..512);
    // flow-control reads cast to int; LDS tag mirrors stale => slow poll.
    gru_pipeline<<<dim3(28), dim3(512), 0, stream>>>(x, wihl0, wihrest, whh, out,
                                                     gring, hhb, tags);
}